// Round 3
// baseline (792.059 us; speedup 1.0000x reference)
//
#include <hip/hip_runtime.h>
#include <hip/hip_cooperative_groups.h>
namespace cg = cooperative_groups;

#define NN 50000
#define DD 64
#define BB 32
#define CHUNKS 32
#define RPB 1568          // rows per block; 32*1568 = 50176 >= 50000
#define ITERS (RPB / 16)  // 98 iterations of 16 rows

// One fused cooperative kernel:
//  phase 1: p = adj ? exp(leaky(tgt + x.a_src)) : 0  -> LDS stash + per-block sum
//  grid.sync()
//  phase 2: out = p * (1/sum_b)  -- single coalesced write, no intermediate global p
__global__ __launch_bounds__(256) void attn_fused(
    const float* __restrict__ x, const float* __restrict__ a,
    const int* __restrict__ node_index, const int* __restrict__ adj,
    float* __restrict__ out, float* __restrict__ pbs /* [BB][CHUNKS] in d_ws */)
{
    const int tid = threadIdx.x;
    const int chunk = blockIdx.x;   // 0..31
    const int b = blockIdx.y;       // 0..31
    const int node = *node_index;

    __shared__ float p_stash[RPB];  // 6.3 KB
    __shared__ float sh_tgt;
    __shared__ float sh_part[4];
    __shared__ float sh_inv;

    // target score: dot(x[b,node,:], a[:64]) — L2-hot after first block of each b
    if (tid < 64) {
        float v = x[(size_t)b * NN * DD + (size_t)node * DD + tid] * a[tid];
        #pragma unroll
        for (int o = 32; o >= 1; o >>= 1) v += __shfl_xor(v, o, 64);
        if (tid == 0) sh_tgt = v;
    }
    __syncthreads();
    const float tgt = sh_tgt;

    const int wave = tid >> 6;   // 0..3
    const int lane = tid & 63;
    const int g = lane >> 4;     // row-within-group 0..3
    const int c = lane & 15;     // 16 lanes x float4 = 64 floats per row

    const float4 av = ((const float4*)(a + DD))[c];
    const int rowBase = chunk * RPB;
    const float* xb = x + (size_t)b * NN * DD;

    float local = 0.f;
    for (int i = 0; i < ITERS; i++) {
        const int lrow = i * 16 + wave * 4 + g;
        const int row = rowBase + lrow;
        const bool valid = (row < NN);
        const int msk = valid ? adj[row] : 0;   // broadcast within row-group

        float s = 0.f;
        if (msk > 0) {  // skip 256 B x-row for masked rows (~50%)
            const float4 xv = ((const float4*)(xb + (size_t)row * DD))[c];
            s = xv.x * av.x + xv.y * av.y + xv.z * av.z + xv.w * av.w;
        }
        s += __shfl_xor(s, 1, 64);
        s += __shfl_xor(s, 2, 64);
        s += __shfl_xor(s, 4, 64);
        s += __shfl_xor(s, 8, 64);

        if (c == 0) {
            float p = 0.f;
            if (msk > 0) {
                const float z = tgt + s;
                const float e = (z > 0.f) ? z : 0.01f * z;
                p = __expf(e);
            }
            p_stash[lrow] = p;
            local += p;
        }
    }

    #pragma unroll
    for (int o = 32; o >= 1; o >>= 1) local += __shfl_xor(local, o, 64);
    if (lane == 0) sh_part[wave] = local;
    __syncthreads();
    if (tid == 0)
        pbs[b * CHUNKS + chunk] = sh_part[0] + sh_part[1] + sh_part[2] + sh_part[3];

    __threadfence();          // make pbs store device-visible before barrier
    cg::this_grid().sync();

    // reduce the 32 chunk partials for this b (tiny, L2-hot)
    if (tid < 32) {
        float v = pbs[b * CHUNKS + tid];
        #pragma unroll
        for (int o = 16; o >= 1; o >>= 1) v += __shfl_xor(v, o, 64);
        if (tid == 0) sh_inv = 1.0f / v;
    }
    __syncthreads();
    const float inv = sh_inv;

    // single coalesced out-write; masked rows stay exactly 0
    for (int li = tid; li < RPB; li += 256) {
        const int row = rowBase + li;
        if (row < NN) out[(size_t)b * NN + row] = p_stash[li] * inv;
    }
}

extern "C" void kernel_launch(void* const* d_in, const int* in_sizes, int n_in,
                              void* d_out, int out_size, void* d_ws, size_t ws_size,
                              hipStream_t stream) {
    const float* x = (const float*)d_in[0];         // (B, N, D) fp32
    const float* a = (const float*)d_in[1];         // (2D, 1) fp32
    const int* node_index = (const int*)d_in[2];    // scalar
    const int* adj = (const int*)d_in[3];           // (N,) int32
    float* out = (float*)d_out;                     // (B, N) fp32
    float* pbs = (float*)d_ws;                      // [32][32] partials (no init needed)

    void* args[] = { (void*)&x, (void*)&a, (void*)&node_index, (void*)&adj,
                     (void*)&out, (void*)&pbs };
    dim3 grid(CHUNKS, BB);   // 1024 blocks = 4/CU on 256 CUs — co-resident
    dim3 block(256);
    hipLaunchCooperativeKernel((void*)attn_fused, grid, block, args, 0, stream);
}

// Round 4
// 506.790 us; speedup vs baseline: 1.5629x; 1.5629x over previous
//
#include <hip/hip_runtime.h>

#define NN 50000
#define DD 64
#define BB 32
#define TILE 256

// Pass 1: p[b,n] = adj[n] ? exp(leaky_relu(tgt[b] + x[b,n,:].a_src)) : 0
// Latency-optimized: adj tile preloaded to LDS (no global dep before x-load),
// 8 independent x row-group loads in flight per wave, coalesced LDS-staged out-write.
__global__ __launch_bounds__(256) void attn_pass1(
    const float* __restrict__ x, const float* __restrict__ a,
    const int* __restrict__ node_index, const int* __restrict__ adj,
    float* __restrict__ out, float* __restrict__ sums)
{
    const int tid = threadIdx.x;
    const int b = blockIdx.y;
    const int rowBase = blockIdx.x * TILE;
    const int node = *node_index;

    __shared__ int   sh_adj[TILE];
    __shared__ float sh_p[TILE];
    __shared__ float sh_tgt;
    __shared__ float sh_part[4];

    // coalesced adj tile -> LDS (one 4 B load per thread)
    {
        const int r = rowBase + tid;
        sh_adj[tid] = (r < NN) ? adj[r] : 0;
    }

    // target score: dot(x[b,node,:], a[:64]) — wave 0, L2-hot after first block
    if (tid < 64) {
        float v = x[(size_t)b * NN * DD + (size_t)node * DD + tid] * a[tid];
        #pragma unroll
        for (int o = 32; o >= 1; o >>= 1) v += __shfl_xor(v, o, 64);
        if (tid == 0) sh_tgt = v;
    }
    __syncthreads();
    const float tgt = sh_tgt;

    const int wave = tid >> 6;   // 0..3, owns 64 rows of the tile
    const int lane = tid & 63;
    const int g = lane >> 4;     // row-within-group 0..3
    const int c = lane & 15;     // 16 lanes x float4 = 64 floats per row

    const float4 av = ((const float4*)(a + DD))[c];
    const float* xb = x + (size_t)b * NN * DD;

    float local = 0.f;

    #pragma unroll
    for (int h = 0; h < 2; h++) {
        int   msk[8];
        float4 xv[8];
        // issue 8 independent masked loads (masks come from LDS, not global)
        #pragma unroll
        for (int u = 0; u < 8; u++) {
            const int lrow = wave * 64 + h * 32 + u * 4 + g;
            msk[u] = sh_adj[lrow];
            if (msk[u] > 0) {
                const size_t row = (size_t)(rowBase + lrow);
                xv[u] = ((const float4*)(xb + row * DD))[c];
            } else {
                xv[u] = make_float4(0.f, 0.f, 0.f, 0.f);
            }
        }
        // consume: dot + 16-lane reduce per row-group
        #pragma unroll
        for (int u = 0; u < 8; u++) {
            float s = xv[u].x * av.x + xv[u].y * av.y + xv[u].z * av.z + xv[u].w * av.w;
            s += __shfl_xor(s, 1, 64);
            s += __shfl_xor(s, 2, 64);
            s += __shfl_xor(s, 4, 64);
            s += __shfl_xor(s, 8, 64);
            if (c == 0) {
                const int lrow = wave * 64 + h * 32 + u * 4 + g;
                float p = 0.f;
                if (msk[u] > 0) {
                    const float z = tgt + s;
                    const float e = (z > 0.f) ? z : 0.01f * z;
                    p = __expf(e);
                }
                sh_p[lrow] = p;
                local += p;
            }
        }
    }

    // block sum (local nonzero only on c==0 lanes)
    #pragma unroll
    for (int o = 32; o >= 1; o >>= 1) local += __shfl_xor(local, o, 64);
    if (lane == 0) sh_part[wave] = local;
    __syncthreads();
    if (tid == 0)
        atomicAdd(&sums[b], sh_part[0] + sh_part[1] + sh_part[2] + sh_part[3]);

    // coalesced out-write of the whole tile
    {
        const int r = rowBase + tid;
        if (r < NN) out[(size_t)b * NN + r] = sh_p[tid];
    }
}

// Pass 2: out[b,n] /= sums[b]   (float4-vectorized, ~12.8 MB RW)
__global__ __launch_bounds__(256) void attn_pass2(
    float* __restrict__ out, const float* __restrict__ sums)
{
    const int N4 = NN / 4;  // 12500
    const int f = blockIdx.x * blockDim.x + threadIdx.x;
    const int b = blockIdx.y;
    if (f < N4) {
        const float inv = 1.0f / sums[b];
        float4* p = (float4*)out + (size_t)b * N4 + f;
        float4 v = *p;
        v.x *= inv; v.y *= inv; v.z *= inv; v.w *= inv;
        *p = v;
    }
}

extern "C" void kernel_launch(void* const* d_in, const int* in_sizes, int n_in,
                              void* d_out, int out_size, void* d_ws, size_t ws_size,
                              hipStream_t stream) {
    const float* x = (const float*)d_in[0];         // (B, N, D) fp32
    const float* a = (const float*)d_in[1];         // (2D, 1) fp32
    const int* node_index = (const int*)d_in[2];    // scalar
    const int* adj = (const int*)d_in[3];           // (N,) int32
    float* out = (float*)d_out;                     // (B, N) fp32
    float* sums = (float*)d_ws;                     // 32 floats of scratch

    hipMemsetAsync(sums, 0, BB * sizeof(float), stream);

    dim3 g1((NN + TILE - 1) / TILE, BB);   // (196, 32)
    attn_pass1<<<g1, 256, 0, stream>>>(x, a, node_index, adj, out, sums);

    dim3 g2((NN / 4 + 255) / 256, BB);
    attn_pass2<<<g2, 256, 0, stream>>>(out, sums);
}

// Round 5
// 493.934 us; speedup vs baseline: 1.6036x; 1.0260x over previous
//
#include <hip/hip_runtime.h>

#define NN 50000
#define DD 64
#define BB 32
#define TILE 256
#define NPB ((NN + TILE - 1) / TILE)   // 196 blocks per batch

// Pass 1: p[b,n] = adj[n] ? exp(leaky_relu(tgt[b] + x[b,n,:].a_src)) : 0
// Layout: 4 lanes per row (4x float4 each) -> only 2 shuffles per row reduce.
// adj tile in LDS (no global dep on the x critical path); ~50% x rows skipped.
// Per-block sums go to unique d_ws slots (no memset, no atomics).
__global__ __launch_bounds__(256) void attn_pass1(
    const float* __restrict__ x, const float* __restrict__ a,
    const int* __restrict__ node_index, const int* __restrict__ adj,
    float* __restrict__ out, float* __restrict__ pbs /* [BB][NPB] */)
{
    const int tid = threadIdx.x;
    const int b = blockIdx.y;
    const int rowBase = blockIdx.x * TILE;
    const int node = *node_index;

    __shared__ int   sh_adj[TILE];
    __shared__ float sh_p[TILE];
    __shared__ float sh_tgt;
    __shared__ float sh_part[4];

    {   // coalesced adj tile -> LDS
        const int r = rowBase + tid;
        sh_adj[tid] = (r < NN) ? adj[r] : 0;
    }

    // target score: dot(x[b,node,:], a[:64]) — wave 0, L2-hot after first block
    if (tid < 64) {
        float v = x[(size_t)b * NN * DD + (size_t)node * DD + tid] * a[tid];
        #pragma unroll
        for (int o = 32; o >= 1; o >>= 1) v += __shfl_xor(v, o, 64);
        if (tid == 0) sh_tgt = v;
    }
    __syncthreads();
    const float tgt = sh_tgt;

    const int wave = tid >> 6;   // 0..3, owns 64 rows
    const int lane = tid & 63;
    const int c  = lane & 3;     // col group: float4s {c, c+4, c+8, c+12}
    const int rg = lane >> 2;    // row within 16-row iteration

    const float4* a4 = (const float4*)(a + DD);
    const float4 av0 = a4[c + 0];
    const float4 av1 = a4[c + 4];
    const float4 av2 = a4[c + 8];
    const float4 av3 = a4[c + 12];

    const float* xb = x + (size_t)b * NN * DD;
    float local = 0.f;

    #pragma unroll
    for (int i = 0; i < 4; i++) {
        const int lrow = wave * 64 + i * 16 + rg;
        const int msk = sh_adj[lrow];
        float s = 0.f;
        if (msk > 0) {
            const float4* xr = (const float4*)(xb + (size_t)(rowBase + lrow) * DD);
            const float4 v0 = xr[c + 0];
            const float4 v1 = xr[c + 4];
            const float4 v2 = xr[c + 8];
            const float4 v3 = xr[c + 12];
            s  = v0.x * av0.x + v0.y * av0.y + v0.z * av0.z + v0.w * av0.w;
            s += v1.x * av1.x + v1.y * av1.y + v1.z * av1.z + v1.w * av1.w;
            s += v2.x * av2.x + v2.y * av2.y + v2.z * av2.z + v2.w * av2.w;
            s += v3.x * av3.x + v3.y * av3.y + v3.z * av3.z + v3.w * av3.w;
        }
        // 4-lane row reduce: 2 shuffles
        s += __shfl_xor(s, 1, 64);
        s += __shfl_xor(s, 2, 64);
        if (c == 0) {
            float p = 0.f;
            if (msk > 0) {
                const float z = tgt + s;
                const float e = (z > 0.f) ? z : 0.01f * z;
                p = __expf(e);
            }
            sh_p[lrow] = p;
            local += p;
        }
    }

    // block sum (local nonzero only on c==0 lanes)
    #pragma unroll
    for (int o = 32; o >= 1; o >>= 1) local += __shfl_xor(local, o, 64);
    if (lane == 0) sh_part[wave] = local;
    __syncthreads();
    if (tid == 0)
        pbs[b * NPB + blockIdx.x] = sh_part[0] + sh_part[1] + sh_part[2] + sh_part[3];

    // coalesced out-write of the whole tile (unnormalized p)
    {
        const int r = rowBase + tid;
        if (r < NN) out[(size_t)b * NN + r] = sh_p[tid];
    }
}

// Pass 2: out[b,n] /= sum_b.  Each block reduces its batch's 196 partials
// (L2-hot, ~0.8 KB) then scales its float4 span.
__global__ __launch_bounds__(256) void attn_pass2(
    float* __restrict__ out, const float* __restrict__ pbs)
{
    const int tid = threadIdx.x;
    const int b = blockIdx.y;
    __shared__ float sh[4];

    float v = (tid < NPB) ? pbs[b * NPB + tid] : 0.f;
    #pragma unroll
    for (int o = 32; o >= 1; o >>= 1) v += __shfl_xor(v, o, 64);
    if ((tid & 63) == 0) sh[tid >> 6] = v;
    __syncthreads();
    const float inv = 1.0f / (sh[0] + sh[1] + sh[2] + sh[3]);

    const int N4 = NN / 4;  // 12500
    const int f = blockIdx.x * blockDim.x + tid;
    if (f < N4) {
        float4* p = (float4*)out + (size_t)b * N4 + f;
        float4 w = *p;
        w.x *= inv; w.y *= inv; w.z *= inv; w.w *= inv;
        *p = w;
    }
}

extern "C" void kernel_launch(void* const* d_in, const int* in_sizes, int n_in,
                              void* d_out, int out_size, void* d_ws, size_t ws_size,
                              hipStream_t stream) {
    const float* x = (const float*)d_in[0];         // (B, N, D) fp32
    const float* a = (const float*)d_in[1];         // (2D, 1) fp32
    const int* node_index = (const int*)d_in[2];    // scalar
    const int* adj = (const int*)d_in[3];           // (N,) int32
    float* out = (float*)d_out;                     // (B, N) fp32
    float* pbs = (float*)d_ws;                      // [32][196] partials, all written

    dim3 g1(NPB, BB);                        // (196, 32)
    attn_pass1<<<g1, 256, 0, stream>>>(x, a, node_index, adj, out, pbs);

    dim3 g2((NN / 4 + 255) / 256, BB);       // (49, 32)
    attn_pass2<<<g2, 256, 0, stream>>>(out, pbs);
}